// Round 13
// baseline (189.799 us; speedup 1.0000x reference)
//
#include <hip/hip_runtime.h>

// DCNv2 forward: B=4, Cin=64, Cout=64, K=3, H=W=128, S=1, P=1
constexpr int B    = 4;
constexpr int Cin  = 64;
constexpr int Cout = 64;
constexpr int H    = 128;
constexpr int W    = 128;
constexpr int KK   = 9;
constexpr int HW   = H * W;
constexpr int OFF_C = 18;                       // mask channels unused by reference
constexpr int OFFSET_ELEMS = B * OFF_C * HW;
constexpr int CK   = Cin * KK;                  // 576
constexpr int SAMP_STRIDE = CK + 8;             // 584 ushorts
constexpr int PIX  = 16;                        // pixels per fused block
constexpr int NT8  = KK * PIX * 8;              // 1152 thread-tasks (8 subs of 8ch)

typedef __attribute__((ext_vector_type(8))) short          short8;
typedef __attribute__((ext_vector_type(8))) unsigned short ushort8;
typedef __attribute__((ext_vector_type(4))) float          f32x4;

// ---- workspace layout (bf16 NHWC tensors + reordered bf16 weights) ----
constexpr size_t XT_OFF  = 0;                               // x_t[B][H][W][64] bf16
constexpr size_t XT_SZ   = (size_t)B * HW * 64 * 2;
constexpr size_t OT_OFF  = XT_OFF + XT_SZ;                  // o_t NHWC bf16
constexpr size_t OT_SZ   = XT_SZ;
constexpr size_t WB_OFF  = OT_OFF + OT_SZ;                  // wb16[64][576], ck' = k*64+c
constexpr size_t WB_SZ   = (size_t)64 * CK * 2;
constexpr size_t CMB_OFF = WB_OFF + WB_SZ;                  // cmb16[32][576], rows>=18 zero
constexpr size_t CMB_SZ  = (size_t)32 * CK * 2;
constexpr size_t WS_NEEDED = CMB_OFF + CMB_SZ;

__device__ __forceinline__ unsigned short f2bf(float f) {   // round-to-nearest-even
    unsigned u = __builtin_bit_cast(unsigned, f);
    u += 0x7FFFu + ((u >> 16) & 1u);
    return (unsigned short)(u >> 16);
}
__device__ __forceinline__ float bf2f(unsigned short h) {
    unsigned u = (unsigned)h << 16;
    return __builtin_bit_cast(float, u);
}

// ============ prep: NCHW fp32 -> NHWC bf16 (x, offset_in) + weight reorder ============
__global__ __launch_bounds__(256)
void prep_all(const float* __restrict__ x, const float* __restrict__ oin,
              const float* __restrict__ wgt, const float* __restrict__ cmw,
              unsigned short* __restrict__ x_t, unsigned short* __restrict__ o_t,
              unsigned short* __restrict__ wb16, unsigned short* __restrict__ cmb16)
{
    __shared__ float tile[64][68];
    int idx = blockIdx.x;
    int t = threadIdx.x;
    if (idx < 2048) {                 // transpose: bit10 = tensor, bits 8-9 = b, 1-7 = h, 0 = wtile
        int tensor = idx >> 10;
        int blk = idx & 1023;
        int wt = blk & 1, h = (blk >> 1) & (H - 1), b = blk >> 8;
        const float* src = (tensor ? oin : x) + (size_t)b * Cin * HW + h * W + wt * 64;
        unsigned short* dst = (tensor ? o_t : x_t) + ((size_t)(b * H + h) * W + wt * 64) * 64;
        int lane16 = t & 15, grp = t >> 4;
        #pragma unroll
        for (int i = 0; i < 4; ++i) {
            int c = grp + 16 * i;
            float4 v = *reinterpret_cast<const float4*>(&src[c * HW + lane16 * 4]);
            int w0 = lane16 * 4;
            tile[w0 + 0][c] = v.x; tile[w0 + 1][c] = v.y;
            tile[w0 + 2][c] = v.z; tile[w0 + 3][c] = v.w;
        }
        __syncthreads();
        #pragma unroll
        for (int i = 0; i < 4; ++i) {
            int w = grp + 16 * i;
            const float* tr = &tile[w][lane16 * 4];
            ushort4 o4;
            o4.x = f2bf(tr[0]); o4.y = f2bf(tr[1]); o4.z = f2bf(tr[2]); o4.w = f2bf(tr[3]);
            *reinterpret_cast<ushort4*>(&dst[(size_t)w * 64 + lane16 * 4]) = o4;
        }
    } else {                          // weight prep: 64 blocks
        int i0 = (idx - 2048) * 256 + t;
        int stride = 64 * 256;
        for (int i = i0; i < 64 * CK; i += stride) {
            int o = i / CK, ckp = i - o * CK;
            int k = ckp >> 6, c = ckp & 63;
            wb16[i] = f2bf(wgt[(o * 64 + c) * 9 + k]);
        }
        for (int i = i0; i < 32 * CK; i += stride) {
            int o = i / CK, ckp = i - o * CK;
            int k = ckp >> 6, c = ckp & 63;
            cmb16[i] = (o < OFF_C) ? f2bf(cmw[(o * 64 + c) * 9 + k]) : (unsigned short)0;
        }
    }
}

// ============ fused: offset-conv MFMA -> register-direct sample+MFMA (no samp LDS) ============
// 4096 blocks x 256 thr. A1/A2 as R10; then each wave samples the block's 16 px itself
// (redundant 4x, L1-hot) and computes its own 16-oc tile. No second barrier, no samp staging.
__global__ __launch_bounds__(256, 4)
void dcn_fused(const unsigned short* __restrict__ x_t,
               const unsigned short* __restrict__ o_t,
               const unsigned short* __restrict__ wb16,
               const unsigned short* __restrict__ cmb16,
               const float* __restrict__ cmb,     // (27,)
               const float* __restrict__ bias,    // (64,)
               float* __restrict__ offs_out,      // (B,18,H,W)
               float* __restrict__ y_out)         // (B,64,H,W)
{
    __shared__ unsigned short stage[PIX][SAMP_STRIDE];   // 18,688 B: o_t im2col patch
    __shared__ float offs_l[OFF_C][PIX];                 // 1,152 B -> total 19,840 B

    // XCD-chunked swizzle: 4096 blocks, 8 XCDs -> contiguous 512-block chunks per XCD.
    int bid = blockIdx.x;
    int blk = (bid & 7) * 512 + (bid >> 3);

    int wc = blk & 7, h = (blk >> 3) & (H - 1), b = blk >> 10;
    int w0 = wc * 16;
    int tid = threadIdx.x;
    int wv = tid >> 6, lane = tid & 63;
    int l16 = lane & 15, q = lane >> 4;

    // ---- phase A1: im2col of o_t into stage (144 tasks x 8 subs of 8ch) ----
    {
        auto loadA = [&](int i) -> ushort8 {
            int sub = i & 7, task = i >> 3;
            int p = task & 15, k = task >> 4;
            int ky = k / 3, kx = k - ky * 3;
            int yy = h + ky - 1;
            int xx = w0 + p + kx - 1;
            ushort8 v = {0, 0, 0, 0, 0, 0, 0, 0};
            if ((unsigned)yy < (unsigned)H && (unsigned)xx < (unsigned)W)
                v = *reinterpret_cast<const ushort8*>(&o_t[((size_t)(b * H + yy) * W + xx) * 64 + sub * 8]);
            return v;
        };
        auto stA = [&](int i, ushort8 v) {
            int sub = i & 7, task = i >> 3;
            int p = task & 15, k = task >> 4;
            *reinterpret_cast<ushort8*>(&stage[p][k * 64 + sub * 8]) = v;
        };
        ushort8 t0 = loadA(tid);
        ushort8 t1 = loadA(tid + 256);
        ushort8 t2 = loadA(tid + 512);
        ushort8 t3 = loadA(tid + 768);
        ushort8 t4 = {0, 0, 0, 0, 0, 0, 0, 0};
        bool tail = tid < NT8 - 1024;          // 128
        if (tail) t4 = loadA(tid + 1024);
        stA(tid, t0); stA(tid + 256, t1); stA(tid + 512, t2); stA(tid + 768, t3);
        if (tail) stA(tid + 1024, t4);
    }
    __syncthreads();

    // ---- phase A2: offset conv MFMA on waves 0-1; C[32ch][16px] ----
    if (wv < 2) {
        int mt = wv;
        f32x4 acc = {0.f, 0.f, 0.f, 0.f};
        const unsigned short* crow = cmb16 + (size_t)(mt * 16 + l16) * CK;
        const unsigned short* brow = &stage[l16][0];
        #pragma unroll 6
        for (int ks = 0; ks < 18; ++ks) {
            short8 a  = *reinterpret_cast<const short8*>(&crow[ks * 32 + q * 8]);
            short8 bb = *reinterpret_cast<const short8*>(&brow[ks * 32 + q * 8]);
            acc = __builtin_amdgcn_mfma_f32_16x16x32_bf16(a, bb, acc, 0, 0, 0);
        }
        #pragma unroll
        for (int r = 0; r < 4; ++r) {                   // D: col=lane&15, row=(lane>>4)*4+r
            int o = mt * 16 + q * 4 + r;
            if (o < OFF_C) {
                float v = acc[r] + cmb[o];
                offs_l[o][l16] = v;
                offs_out[((size_t)(b * OFF_C + o) * H + h) * W + w0 + l16] = v;
            }
        }
    }
    __syncthreads();

    // ---- phase CD: register-direct sample + MFMA, no staging, no more barriers ----
    int px = w0 + l16;                     // this lane's pixel

    // bilinear meta for 9 taps, packed: addr(22b) | dy(1) | dx(1) | valid(4)
    int   ma[9];
    float mwy[9], mwx[9];
    #pragma unroll
    for (int k = 0; k < 9; ++k) {
        int ky = k / 3, kx = k - ky * 3;
        float dyv = offs_l[2 * k][l16];
        float dxv = offs_l[2 * k + 1][l16];
        float py  = dyv + (float)(h - 1 + ky);
        float pxf = dxv + (float)(px - 1 + kx);
        float fy = floorf(py), fx = floorf(pxf);
        int iy = (int)fy, ix = (int)fx;
        mwy[k] = py - fy;
        mwx[k] = pxf - fx;
        bool y0 = (unsigned)iy       < (unsigned)H;
        bool y1 = (unsigned)(iy + 1) < (unsigned)H;
        bool x0 = (unsigned)ix       < (unsigned)W;
        bool x1 = (unsigned)(ix + 1) < (unsigned)W;
        int cy0 = min(max(iy, 0), H - 1),     cy1 = min(max(iy + 1, 0), H - 1);
        int cx0 = min(max(ix, 0), W - 1),     cx1 = min(max(ix + 1, 0), W - 1);
        int a00 = ((b * H + cy0) * W + cx0) * 64;           // < 2^22
        ma[k] = a00 | ((cy1 - cy0) << 22) | ((cx1 - cx0) << 23)
                    | ((int)(y0 && x0) << 24) | ((int)(y0 && x1) << 25)
                    | ((int)(y1 && x0) << 26) | ((int)(y1 && x1) << 27);
    }

    f32x4 acc = {0.f, 0.f, 0.f, 0.f};
    const unsigned short* arow = wb16 + (size_t)(wv * 16 + l16) * CK;

    auto ISSUE = [&](int ks, uint4& v00, uint4& v01, uint4& v10, uint4& v11) {
        int k  = ks >> 1;
        int c0 = (ks & 1) * 32 + q * 8;
        int m  = ma[k];
        int a00 = (m & 0x3FFFFF) + c0;
        int dyo = (m & (1 << 22)) ? W * 64 : 0;
        int dxo = (m & (1 << 23)) ? 64 : 0;
        v00 = *reinterpret_cast<const uint4*>(&x_t[a00]);
        v01 = *reinterpret_cast<const uint4*>(&x_t[a00 + dxo]);
        v10 = *reinterpret_cast<const uint4*>(&x_t[a00 + dyo]);
        v11 = *reinterpret_cast<const uint4*>(&x_t[a00 + dyo + dxo]);
    };
    auto STEP = [&](int ks, uint4 v00, uint4 v01, uint4 v10, uint4 v11) {
        int k = ks >> 1;
        int m = ma[k];
        float wy = mwy[k], wx = mwx[k];
        float omy = 1.f - wy, omx = 1.f - wx;
        float w00 = (m & (1 << 24)) ? omy * omx : 0.f;
        float w01 = (m & (1 << 25)) ? omy * wx  : 0.f;
        float w10 = (m & (1 << 26)) ? wy * omx  : 0.f;
        float w11 = (m & (1 << 27)) ? wy * wx   : 0.f;
        auto bl2 = [&](unsigned u00, unsigned u01, unsigned u10, unsigned u11) -> unsigned {
            float lo = w00 * bf2f((unsigned short)u00) + w01 * bf2f((unsigned short)u01)
                     + w10 * bf2f((unsigned short)u10) + w11 * bf2f((unsigned short)u11);
            float hi = w00 * bf2f((unsigned short)(u00 >> 16)) + w01 * bf2f((unsigned short)(u01 >> 16))
                     + w10 * bf2f((unsigned short)(u10 >> 16)) + w11 * bf2f((unsigned short)(u11 >> 16));
            return (unsigned)f2bf(lo) | ((unsigned)f2bf(hi) << 16);
        };
        uint4 bu;
        bu.x = bl2(v00.x, v01.x, v10.x, v11.x);
        bu.y = bl2(v00.y, v01.y, v10.y, v11.y);
        bu.z = bl2(v00.z, v01.z, v10.z, v11.z);
        bu.w = bl2(v00.w, v01.w, v10.w, v11.w);
        short8 bfrag = __builtin_bit_cast(short8, bu);
        short8 af = *reinterpret_cast<const short8*>(&arow[ks * 32 + q * 8]);
        acc = __builtin_amdgcn_mfma_f32_16x16x32_bf16(af, bfrag, acc, 0, 0, 0);
    };

    {   // 2-deep rotated pipeline over 18 K-steps (named regs, rule #20-safe)
        uint4 A0, A1v, A2v, A3v, B0, B1v, B2v, B3v;
        ISSUE(0, A0, A1v, A2v, A3v);
        ISSUE(1, B0, B1v, B2v, B3v);
        STEP(0, A0, A1v, A2v, A3v);   ISSUE(2,  A0, A1v, A2v, A3v);
        STEP(1, B0, B1v, B2v, B3v);   ISSUE(3,  B0, B1v, B2v, B3v);
        STEP(2, A0, A1v, A2v, A3v);   ISSUE(4,  A0, A1v, A2v, A3v);
        STEP(3, B0, B1v, B2v, B3v);   ISSUE(5,  B0, B1v, B2v, B3v);
        STEP(4, A0, A1v, A2v, A3v);   ISSUE(6,  A0, A1v, A2v, A3v);
        STEP(5, B0, B1v, B2v, B3v);   ISSUE(7,  B0, B1v, B2v, B3v);
        STEP(6, A0, A1v, A2v, A3v);   ISSUE(8,  A0, A1v, A2v, A3v);
        STEP(7, B0, B1v, B2v, B3v);   ISSUE(9,  B0, B1v, B2v, B3v);
        STEP(8, A0, A1v, A2v, A3v);   ISSUE(10, A0, A1v, A2v, A3v);
        STEP(9, B0, B1v, B2v, B3v);   ISSUE(11, B0, B1v, B2v, B3v);
        STEP(10, A0, A1v, A2v, A3v);  ISSUE(12, A0, A1v, A2v, A3v);
        STEP(11, B0, B1v, B2v, B3v);  ISSUE(13, B0, B1v, B2v, B3v);
        STEP(12, A0, A1v, A2v, A3v);  ISSUE(14, A0, A1v, A2v, A3v);
        STEP(13, B0, B1v, B2v, B3v);  ISSUE(15, B0, B1v, B2v, B3v);
        STEP(14, A0, A1v, A2v, A3v);  ISSUE(16, A0, A1v, A2v, A3v);
        STEP(15, B0, B1v, B2v, B3v);  ISSUE(17, B0, B1v, B2v, B3v);
        STEP(16, A0, A1v, A2v, A3v);
        STEP(17, B0, B1v, B2v, B3v);
    }

    // D layout: col = lane&15 (= px), row = q*4 + r within this wave's 16-oc tile
    #pragma unroll
    for (int r = 0; r < 4; ++r) {
        int o = wv * 16 + q * 4 + r;
        y_out[((size_t)(b * Cout + o) * H + h) * W + px] = acc[r] + bias[o];
    }
}

// ======================= fallback fp32 path (round-1 kernels) =======================
__global__ __launch_bounds__(256)
void offset_conv_fb(const float* __restrict__ oin, const float* __restrict__ cmw,
                    const float* __restrict__ cmb, float* __restrict__ offs)
{
    int t = blockIdx.x * 256 + threadIdx.x;
    int w = t & (W - 1);
    int h = (t >> 7) & (H - 1);
    int oc = (t >> 14) % OFF_C;
    int b  = (t >> 14) / OFF_C;
    float acc = cmb[oc];
    const float* wrow  = cmw + oc * Cin * KK;
    const float* ibase = oin + b * Cin * HW;
    for (int c = 0; c < Cin; ++c) {
        const float* ip = ibase + c * HW;
        const float* wp = wrow + c * KK;
        #pragma unroll
        for (int ky = 0; ky < 3; ++ky) {
            int yy = h + ky - 1;
            if ((unsigned)yy >= (unsigned)H) continue;
            #pragma unroll
            for (int kx = 0; kx < 3; ++kx) {
                int xx = w + kx - 1;
                if ((unsigned)xx >= (unsigned)W) continue;
                acc = fmaf(ip[yy * W + xx], wp[ky * 3 + kx], acc);
            }
        }
    }
    offs[t] = acc;
}

__global__ __launch_bounds__(256)
void deform_gemm_fb(const float* __restrict__ x, const float* __restrict__ offs,
                    const float* __restrict__ wgt, const float* __restrict__ bias,
                    float* __restrict__ y)
{
    __shared__ float samp[16][580];
    __shared__ int   s_iy[144];
    __shared__ int   s_ix[144];
    __shared__ float s_wy[144];
    __shared__ float s_wx[144];
    int blk = blockIdx.x;
    int wchunk = blk & 7;
    int h = (blk >> 3) & (H - 1);
    int b = blk >> 10;
    int w0 = wchunk * 16;
    int tid = threadIdx.x;
    if (tid < 144) {
        int p = tid & 15, k = tid >> 4;
        int w = w0 + p;
        float dyv = offs[((b * OFF_C + 2 * k    ) * H + h) * W + w];
        float dxv = offs[((b * OFF_C + 2 * k + 1) * H + h) * W + w];
        float py = dyv + (float)(h - 1 + k / 3);
        float px = dxv + (float)(w - 1 + k % 3);
        float fy = floorf(py), fx = floorf(px);
        s_iy[tid] = (int)fy; s_ix[tid] = (int)fx;
        s_wy[tid] = py - fy; s_wx[tid] = px - fx;
    }
    __syncthreads();
    const float* xb = x + b * Cin * HW;
    for (int i = tid; i < Cin * KK * 16; i += 256) {
        int p = i & 15;
        int k = (i >> 4) % KK;
        int c = i / (KK * 16);
        int m = k * 16 + p;
        int iy = s_iy[m], ix = s_ix[m];
        float wy = s_wy[m], wx = s_wx[m];
        const float* xp = xb + c * HW;
        float v00 = 0.f, v01 = 0.f, v10 = 0.f, v11 = 0.f;
        bool y0ok = (unsigned)iy       < (unsigned)H;
        bool y1ok = (unsigned)(iy + 1) < (unsigned)H;
        bool x0ok = (unsigned)ix       < (unsigned)W;
        bool x1ok = (unsigned)(ix + 1) < (unsigned)W;
        if (y0ok && x0ok) v00 = xp[iy * W + ix];
        if (y0ok && x1ok) v01 = xp[iy * W + ix + 1];
        if (y1ok && x0ok) v10 = xp[(iy + 1) * W + ix];
        if (y1ok && x1ok) v11 = xp[(iy + 1) * W + ix + 1];
        samp[p][c * KK + k] = (v00 * (1.f - wx) + v01 * wx) * (1.f - wy)
                            + (v10 * (1.f - wx) + v11 * wx) * wy;
    }
    __syncthreads();
    int tp = tid & 15, to = tid >> 4;
    float acc0 = 0.f, acc1 = 0.f, acc2 = 0.f, acc3 = 0.f;
    for (int ck = 0; ck < CK; ck += 4) {
        float4 sv = *reinterpret_cast<const float4*>(&samp[tp][ck]);
        const float4 w0v = *reinterpret_cast<const float4*>(&wgt[(0 * 16 + to) * CK + ck]);
        const float4 w1v = *reinterpret_cast<const float4*>(&wgt[(1 * 16 + to) * CK + ck]);
        const float4 w2v = *reinterpret_cast<const float4*>(&wgt[(2 * 16 + to) * CK + ck]);
        const float4 w3v = *reinterpret_cast<const float4*>(&wgt[(3 * 16 + to) * CK + ck]);
        acc0 = fmaf(sv.x, w0v.x, acc0); acc0 = fmaf(sv.y, w0v.y, acc0);
        acc0 = fmaf(sv.z, w0v.z, acc0); acc0 = fmaf(sv.w, w0v.w, acc0);
        acc1 = fmaf(sv.x, w1v.x, acc1); acc1 = fmaf(sv.y, w1v.y, acc1);
        acc1 = fmaf(sv.z, w1v.z, acc1); acc1 = fmaf(sv.w, w1v.w, acc1);
        acc2 = fmaf(sv.x, w2v.x, acc2); acc2 = fmaf(sv.y, w2v.y, acc2);
        acc2 = fmaf(sv.z, w2v.z, acc2); acc2 = fmaf(sv.w, w2v.w, acc2);
        acc3 = fmaf(sv.x, w3v.x, acc3); acc3 = fmaf(sv.y, w3v.y, acc3);
        acc3 = fmaf(sv.z, w3v.z, acc3); acc3 = fmaf(sv.w, w3v.w, acc3);
    }
    int wcol = w0 + tp;
    y[((b * Cout + (0 * 16 + to)) * H + h) * W + wcol] = acc0 + bias[0 * 16 + to];
    y[((b * Cout + (1 * 16 + to)) * H + h) * W + wcol] = acc1 + bias[1 * 16 + to];
    y[((b * Cout + (2 * 16 + to)) * H + h) * W + wcol] = acc2 + bias[2 * 16 + to];
    y[((b * Cout + (3 * 16 + to)) * H + h) * W + wcol] = acc3 + bias[3 * 16 + to];
}

extern "C" void kernel_launch(void* const* d_in, const int* in_sizes, int n_in,
                              void* d_out, int out_size, void* d_ws, size_t ws_size,
                              hipStream_t stream) {
    const float* x         = (const float*)d_in[0];
    const float* offset_in = (const float*)d_in[1];
    const float* weight    = (const float*)d_in[2];
    const float* bias      = (const float*)d_in[3];
    const float* cm_w      = (const float*)d_in[4];
    const float* cm_b      = (const float*)d_in[5];

    float* out  = (float*)d_out;
    float* offs = out;                    // output 0: (B,18,H,W)
    float* yout = out + OFFSET_ELEMS;     // output 1: (B,64,H,W)

    if (ws_size >= WS_NEEDED) {
        unsigned short* x_t   = (unsigned short*)((char*)d_ws + XT_OFF);
        unsigned short* o_t   = (unsigned short*)((char*)d_ws + OT_OFF);
        unsigned short* wb16  = (unsigned short*)((char*)d_ws + WB_OFF);
        unsigned short* cmb16 = (unsigned short*)((char*)d_ws + CMB_OFF);

        prep_all<<<2048 + 64, 256, 0, stream>>>(x, offset_in, weight, cm_w,
                                                x_t, o_t, wb16, cmb16);
        dcn_fused<<<B * H * (W / PIX), 256, 0, stream>>>(x_t, o_t, wb16, cmb16,
                                                         cm_b, bias, offs, yout);
    } else {
        offset_conv_fb<<<OFFSET_ELEMS / 256, 256, 0, stream>>>(offset_in, cm_w, cm_b, offs);
        deform_gemm_fb<<<B * H * (W / 16), 256, 0, stream>>>(x, offs, weight, bias, yout);
    }
}

// Round 14
// 44.570 us; speedup vs baseline: 4.2584x; 4.2584x over previous
//
#include <hip/hip_runtime.h>

// DCNv2 forward: B=4, Cin=64, Cout=64, K=3, H=W=128, S=1, P=1
constexpr int B    = 4;
constexpr int Cin  = 64;
constexpr int Cout = 64;
constexpr int H    = 128;
constexpr int W    = 128;
constexpr int KK   = 9;
constexpr int HW   = H * W;
constexpr int OFF_C = 18;                       // mask channels unused by reference
constexpr int OFFSET_ELEMS = B * OFF_C * HW;
constexpr int CK   = Cin * KK;                  // 576
constexpr int SAMP_STRIDE = CK + 8;             // 584 ushorts
constexpr int PIX  = 16;                        // pixels per fused block
constexpr int NT8  = KK * PIX * 8;              // 1152 thread-tasks (8 subs of 8ch)

typedef __attribute__((ext_vector_type(8))) short          short8;
typedef __attribute__((ext_vector_type(8))) unsigned short ushort8;
typedef __attribute__((ext_vector_type(4))) float          f32x4;
typedef __attribute__((ext_vector_type(2))) float          f32x2;

// ---- workspace layout ----
// wfrag: [4 wt][18 ks][64 lane][8 ch] bf16 — A-fragments in wave-contiguous order.
// cfrag: [2 wt][18 ks][64 lane][8 ch] bf16 — same for offset-conv weights (o>=18 zero).
constexpr size_t XT_OFF  = 0;                               // x_t[B][H][W][64] bf16
constexpr size_t XT_SZ   = (size_t)B * HW * 64 * 2;
constexpr size_t OT_OFF  = XT_OFF + XT_SZ;                  // o_t NHWC bf16
constexpr size_t OT_SZ   = XT_SZ;
constexpr size_t WB_OFF  = OT_OFF + OT_SZ;                  // wfrag (73,728 B)
constexpr size_t WB_SZ   = (size_t)4 * 18 * 64 * 8 * 2;
constexpr size_t CMB_OFF = WB_OFF + WB_SZ;                  // cfrag (36,864 B)
constexpr size_t CMB_SZ  = (size_t)2 * 18 * 64 * 8 * 2;
constexpr size_t WS_NEEDED = CMB_OFF + CMB_SZ;

__device__ __forceinline__ unsigned short f2bf(float f) {   // round-to-nearest-even
    unsigned u = __builtin_bit_cast(unsigned, f);
    u += 0x7FFFu + ((u >> 16) & 1u);
    return (unsigned short)(u >> 16);
}
__device__ __forceinline__ float bf2f(unsigned short h) {
    unsigned u = (unsigned)h << 16;
    return __builtin_bit_cast(float, u);
}

// packed helpers (VOP3P): 2 f32 lanes per instruction
__device__ __forceinline__ f32x2 pk_mul(f32x2 a, f32x2 b) {
    f32x2 d;
    asm("v_pk_mul_f32 %0, %1, %2" : "=v"(d) : "v"(a), "v"(b));
    return d;
}
__device__ __forceinline__ f32x2 pk_fma(f32x2 a, f32x2 b, f32x2 c) {
    f32x2 d;
    asm("v_pk_fma_f32 %0, %1, %2, %3" : "=v"(d) : "v"(a), "v"(b), "v"(c));
    return d;
}
__device__ __forceinline__ f32x2 up2(unsigned v) {
    f32x2 r;
    r.x = __builtin_bit_cast(float, v << 16);
    r.y = __builtin_bit_cast(float, v & 0xffff0000u);
    return r;
}
__device__ __forceinline__ unsigned cvtpk_bf16(f32x2 v) {
    unsigned r;
    asm("v_cvt_pk_bf16_f32 %0, %1, %2" : "=v"(r) : "v"(v.x), "v"(v.y));
    return r;
}

// ============ prep: NCHW fp32 -> NHWC bf16 (x, offset_in) + fragment-order weights ============
__global__ __launch_bounds__(256)
void prep_all(const float* __restrict__ x, const float* __restrict__ oin,
              const float* __restrict__ wgt, const float* __restrict__ cmw,
              unsigned short* __restrict__ x_t, unsigned short* __restrict__ o_t,
              unsigned short* __restrict__ wfrag, unsigned short* __restrict__ cfrag)
{
    __shared__ float tile[64][68];
    int idx = blockIdx.x;
    int t = threadIdx.x;
    if (idx < 2048) {                 // transpose: bit10 = tensor, bits 8-9 = b, 1-7 = h, 0 = wtile
        int tensor = idx >> 10;
        int blk = idx & 1023;
        int wt = blk & 1, h = (blk >> 1) & (H - 1), b = blk >> 8;
        const float* src = (tensor ? oin : x) + (size_t)b * Cin * HW + h * W + wt * 64;
        unsigned short* dst = (tensor ? o_t : x_t) + ((size_t)(b * H + h) * W + wt * 64) * 64;
        int lane16 = t & 15, grp = t >> 4;
        #pragma unroll
        for (int i = 0; i < 4; ++i) {
            int c = grp + 16 * i;
            float4 v = *reinterpret_cast<const float4*>(&src[c * HW + lane16 * 4]);
            int w0 = lane16 * 4;
            tile[w0 + 0][c] = v.x; tile[w0 + 1][c] = v.y;
            tile[w0 + 2][c] = v.z; tile[w0 + 3][c] = v.w;
        }
        __syncthreads();
        #pragma unroll
        for (int i = 0; i < 4; ++i) {
            int w = grp + 16 * i;
            const float* tr = &tile[w][lane16 * 4];
            ushort4 o4;
            o4.x = f2bf(tr[0]); o4.y = f2bf(tr[1]); o4.z = f2bf(tr[2]); o4.w = f2bf(tr[3]);
            *reinterpret_cast<ushort4*>(&dst[(size_t)w * 64 + lane16 * 4]) = o4;
        }
    } else {                          // weight prep (fragment order): 64 blocks
        int i0 = (idx - 2048) * 256 + t;
        int stride = 64 * 256;
        // wfrag[wt][ks][lane][j]: o = wt*16 + (lane&15); ckp = ks*32 + (lane>>4)*8 + j
        for (int i = i0; i < 4 * 18 * 64 * 8; i += stride) {
            int j    = i & 7;
            int lane = (i >> 3) & 63;
            int ks   = (i >> 9) % 18;
            int wt   = (i >> 9) / 18;
            int o    = wt * 16 + (lane & 15);
            int ckp  = ks * 32 + (lane >> 4) * 8 + j;
            int k = ckp >> 6, c = ckp & 63;
            wfrag[i] = f2bf(wgt[(o * 64 + c) * 9 + k]);
        }
        for (int i = i0; i < 2 * 18 * 64 * 8; i += stride) {
            int j    = i & 7;
            int lane = (i >> 3) & 63;
            int ks   = (i >> 9) % 18;
            int wt   = (i >> 9) / 18;
            int o    = wt * 16 + (lane & 15);
            int ckp  = ks * 32 + (lane >> 4) * 8 + j;
            int k = ckp >> 6, c = ckp & 63;
            cfrag[i] = (o < OFF_C) ? f2bf(cmw[(o * 64 + c) * 9 + k]) : (unsigned short)0;
        }
    }
}

// ============ fused: offset-conv MFMA -> bilinear sample -> main MFMA (PIX=16) ============
// R14 = R10 structure + coalesced fragment-order weight loads (1024B bursts).
__global__ __launch_bounds__(256, 8)
void dcn_fused(const unsigned short* __restrict__ x_t,
               const unsigned short* __restrict__ o_t,
               const unsigned short* __restrict__ wfrag,
               const unsigned short* __restrict__ cfrag,
               const float* __restrict__ cmb,     // (27,)
               const float* __restrict__ bias,    // (64,)
               float* __restrict__ offs_out,      // (B,18,H,W)
               float* __restrict__ y_out)         // (B,64,H,W)
{
    __shared__ unsigned short stage[PIX][SAMP_STRIDE];   // 18,688 B: o_t patch, then samp
    __shared__ float offs_l[OFF_C][PIX];                 // 1,152 B -> total 19,840 B -> 8 blocks/CU

    // XCD-chunked swizzle: 4096 blocks, 8 XCDs -> contiguous 512-block chunks per XCD.
    int bid = blockIdx.x;
    int blk = (bid & 7) * 512 + (bid >> 3);

    int wc = blk & 7, h = (blk >> 3) & (H - 1), b = blk >> 10;
    int w0 = wc * 16;
    int tid = threadIdx.x;
    int wv = tid >> 6, lane = tid & 63;
    int l16 = lane & 15, q = lane >> 4;

    // ---- phase A1: im2col of o_t into stage (144 tasks x 8 subs of 8ch) ----
    {
        auto loadA = [&](int i) -> ushort8 {
            int sub = i & 7, task = i >> 3;
            int p = task & 15, k = task >> 4;
            int ky = k / 3, kx = k - ky * 3;
            int yy = h + ky - 1;
            int xx = w0 + p + kx - 1;
            ushort8 v = {0, 0, 0, 0, 0, 0, 0, 0};
            if ((unsigned)yy < (unsigned)H && (unsigned)xx < (unsigned)W)
                v = *reinterpret_cast<const ushort8*>(&o_t[((size_t)(b * H + yy) * W + xx) * 64 + sub * 8]);
            return v;
        };
        auto stA = [&](int i, ushort8 v) {
            int sub = i & 7, task = i >> 3;
            int p = task & 15, k = task >> 4;
            *reinterpret_cast<ushort8*>(&stage[p][k * 64 + sub * 8]) = v;
        };
        ushort8 t0 = loadA(tid);
        ushort8 t1 = loadA(tid + 256);
        ushort8 t2 = loadA(tid + 512);
        ushort8 t3 = loadA(tid + 768);
        ushort8 t4 = {0, 0, 0, 0, 0, 0, 0, 0};
        bool tail = tid < NT8 - 1024;          // 128
        if (tail) t4 = loadA(tid + 1024);
        stA(tid, t0); stA(tid + 256, t1); stA(tid + 512, t2); stA(tid + 768, t3);
        if (tail) stA(tid + 1024, t4);
    }
    __syncthreads();

    // ---- phase A2: offset conv MFMA on waves 0-1; C[32ch][16px] ----
    if (wv < 2) {
        int mt = wv;
        f32x4 acc = {0.f, 0.f, 0.f, 0.f};
        const unsigned short* crow = cfrag + ((size_t)(mt * 18) * 64 + lane) * 8;
        const unsigned short* brow = &stage[l16][0];
        #pragma unroll 6
        for (int ks = 0; ks < 18; ++ks) {
            short8 a  = *reinterpret_cast<const short8*>(&crow[(size_t)ks * 512]);
            short8 bb = *reinterpret_cast<const short8*>(&brow[ks * 32 + q * 8]);
            acc = __builtin_amdgcn_mfma_f32_16x16x32_bf16(a, bb, acc, 0, 0, 0);
        }
        #pragma unroll
        for (int r = 0; r < 4; ++r) {                   // D: col=lane&15, row=(lane>>4)*4+r
            int o = mt * 16 + q * 4 + r;
            if (o < OFF_C) {
                float v = acc[r] + cmb[o];
                offs_l[o][l16] = v;
                offs_out[((size_t)(b * OFF_C + o) * H + h) * W + w0 + l16] = v;
            }
        }
    }
    __syncthreads();

    // ---- phase C: inline meta + gather + packed blend (v_pk_fma_f32) + cvt_pk pack ----
    {
        auto bodyC = [&](int i) {
            int sub = i & 7, task = i >> 3;
            int p = task & 15, k = task >> 4;
            int ky = k / 3, kx = k - ky * 3;
            int c0 = sub * 8;
            float dyv = offs_l[2 * k][p];
            float dxv = offs_l[2 * k + 1][p];
            float py = dyv + (float)(h - 1 + ky);
            float px = dxv + (float)(w0 + p - 1 + kx);
            float fy = floorf(py), fx = floorf(px);
            int iy = (int)fy, ix = (int)fx;
            float wy = py - fy, wx = px - fx;
            bool y0 = (unsigned)iy       < (unsigned)H;
            bool y1 = (unsigned)(iy + 1) < (unsigned)H;
            bool x0 = (unsigned)ix       < (unsigned)W;
            bool x1 = (unsigned)(ix + 1) < (unsigned)W;
            int cy0 = min(max(iy, 0), H - 1),     cy1 = min(max(iy + 1, 0), H - 1);
            int cx0 = min(max(ix, 0), W - 1),     cx1 = min(max(ix + 1, 0), W - 1);
            int rb = b * H;
            float omy = 1.f - wy, omx = 1.f - wx;
            float w00 = (y0 && x0) ? omy * omx : 0.f;
            float w01 = (y0 && x1) ? omy * wx  : 0.f;
            float w10 = (y1 && x0) ? wy * omx  : 0.f;
            float w11 = (y1 && x1) ? wy * wx   : 0.f;
            uint4 v00 = *reinterpret_cast<const uint4*>(&x_t[((rb + cy0) * W + cx0) * 64 + c0]);
            uint4 v01 = *reinterpret_cast<const uint4*>(&x_t[((rb + cy0) * W + cx1) * 64 + c0]);
            uint4 v10 = *reinterpret_cast<const uint4*>(&x_t[((rb + cy1) * W + cx0) * 64 + c0]);
            uint4 v11 = *reinterpret_cast<const uint4*>(&x_t[((rb + cy1) * W + cx1) * 64 + c0]);
            f32x2 W00 = {w00, w00}, W01 = {w01, w01}, W10 = {w10, w10}, W11 = {w11, w11};
            uint4 o;
            f32x2 a;
            a = pk_mul(up2(v00.x), W00);
            a = pk_fma(up2(v01.x), W01, a);
            a = pk_fma(up2(v10.x), W10, a);
            a = pk_fma(up2(v11.x), W11, a);
            o.x = cvtpk_bf16(a);
            a = pk_mul(up2(v00.y), W00);
            a = pk_fma(up2(v01.y), W01, a);
            a = pk_fma(up2(v10.y), W10, a);
            a = pk_fma(up2(v11.y), W11, a);
            o.y = cvtpk_bf16(a);
            a = pk_mul(up2(v00.z), W00);
            a = pk_fma(up2(v01.z), W01, a);
            a = pk_fma(up2(v10.z), W10, a);
            a = pk_fma(up2(v11.z), W11, a);
            o.z = cvtpk_bf16(a);
            a = pk_mul(up2(v00.w), W00);
            a = pk_fma(up2(v01.w), W01, a);
            a = pk_fma(up2(v10.w), W10, a);
            a = pk_fma(up2(v11.w), W11, a);
            o.w = cvtpk_bf16(a);
            *reinterpret_cast<uint4*>(&stage[p][k * 64 + c0]) = o;
        };
        bodyC(tid);
        bodyC(tid + 256);
        bodyC(tid + 512);
        bodyC(tid + 768);
        if (tid < NT8 - 1024) bodyC(tid + 1024);
    }
    __syncthreads();

    // ---- phase D: main MFMA, 4 waves; C[64ch][16px]; coalesced A-fragment loads ----
    {
        f32x4 acc = {0.f, 0.f, 0.f, 0.f};
        const unsigned short* arow = wfrag + ((size_t)(wv * 18) * 64 + lane) * 8;
        const unsigned short* brow = &stage[l16][0];
        #pragma unroll 6
        for (int ks = 0; ks < 18; ++ks) {
            short8 a  = *reinterpret_cast<const short8*>(&arow[(size_t)ks * 512]);
            short8 bb = *reinterpret_cast<const short8*>(&brow[ks * 32 + q * 8]);
            acc = __builtin_amdgcn_mfma_f32_16x16x32_bf16(a, bb, acc, 0, 0, 0);
        }
        #pragma unroll
        for (int r = 0; r < 4; ++r) {
            int o = wv * 16 + q * 4 + r;
            y_out[((size_t)(b * Cout + o) * H + h) * W + w0 + l16] = acc[r] + bias[o];
        }
    }
}

// ======================= fallback fp32 path (round-1 kernels) =======================
__global__ __launch_bounds__(256)
void offset_conv_fb(const float* __restrict__ oin, const float* __restrict__ cmw,
                    const float* __restrict__ cmb, float* __restrict__ offs)
{
    int t = blockIdx.x * 256 + threadIdx.x;
    int w = t & (W - 1);
    int h = (t >> 7) & (H - 1);
    int oc = (t >> 14) % OFF_C;
    int b  = (t >> 14) / OFF_C;
    float acc = cmb[oc];
    const float* wrow  = cmw + oc * Cin * KK;
    const float* ibase = oin + b * Cin * HW;
    for (int c = 0; c < Cin; ++c) {
        const float* ip = ibase + c * HW;
        const float* wp = wrow + c * KK;
        #pragma unroll
        for (int ky = 0; ky < 3; ++ky) {
            int yy = h + ky - 1;
            if ((unsigned)yy >= (unsigned)H) continue;
            #pragma unroll
            for (int kx = 0; kx < 3; ++kx) {
                int xx = w + kx - 1;
                if ((unsigned)xx >= (unsigned)W) continue;
                acc = fmaf(ip[yy * W + xx], wp[ky * 3 + kx], acc);
            }
        }
    }
    offs[t] = acc;
}

__global__ __launch_bounds__(256)
void deform_gemm_fb(const float* __restrict__ x, const float* __restrict__ offs,
                    const float* __restrict__ wgt, const float* __restrict__ bias,
                    float* __restrict__ y)
{
    __shared__ float samp[16][580];
    __shared__ int   s_iy[144];
    __shared__ int   s_ix[144];
    __shared__ float s_wy[144];
    __shared__ float s_wx[144];
    int blk = blockIdx.x;
    int wchunk = blk & 7;
    int h = (blk >> 3) & (H - 1);
    int b = blk >> 10;
    int w0 = wchunk * 16;
    int tid = threadIdx.x;
    if (tid < 144) {
        int p = tid & 15, k = tid >> 4;
        int w = w0 + p;
        float dyv = offs[((b * OFF_C + 2 * k    ) * H + h) * W + w];
        float dxv = offs[((b * OFF_C + 2 * k + 1) * H + h) * W + w];
        float py = dyv + (float)(h - 1 + k / 3);
        float px = dxv + (float)(w - 1 + k % 3);
        float fy = floorf(py), fx = floorf(px);
        s_iy[tid] = (int)fy; s_ix[tid] = (int)fx;
        s_wy[tid] = py - fy; s_wx[tid] = px - fx;
    }
    __syncthreads();
    const float* xb = x + b * Cin * HW;
    for (int i = tid; i < Cin * KK * 16; i += 256) {
        int p = i & 15;
        int k = (i >> 4) % KK;
        int c = i / (KK * 16);
        int m = k * 16 + p;
        int iy = s_iy[m], ix = s_ix[m];
        float wy = s_wy[m], wx = s_wx[m];
        const float* xp = xb + c * HW;
        float v00 = 0.f, v01 = 0.f, v10 = 0.f, v11 = 0.f;
        bool y0ok = (unsigned)iy       < (unsigned)H;
        bool y1ok = (unsigned)(iy + 1) < (unsigned)H;
        bool x0ok = (unsigned)ix       < (unsigned)W;
        bool x1ok = (unsigned)(ix + 1) < (unsigned)W;
        if (y0ok && x0ok) v00 = xp[iy * W + ix];
        if (y0ok && x1ok) v01 = xp[iy * W + ix + 1];
        if (y1ok && x0ok) v10 = xp[(iy + 1) * W + ix];
        if (y1ok && x1ok) v11 = xp[(iy + 1) * W + ix + 1];
        samp[p][c * KK + k] = (v00 * (1.f - wx) + v01 * wx) * (1.f - wy)
                            + (v10 * (1.f - wx) + v11 * wx) * wy;
    }
    __syncthreads();
    int tp = tid & 15, to = tid >> 4;
    float acc0 = 0.f, acc1 = 0.f, acc2 = 0.f, acc3 = 0.f;
    for (int ck = 0; ck < CK; ck += 4) {
        float4 sv = *reinterpret_cast<const float4*>(&samp[tp][ck]);
        const float4 w0v = *reinterpret_cast<const float4*>(&wgt[(0 * 16 + to) * CK + ck]);
        const float4 w1v = *reinterpret_cast<const float4*>(&wgt[(1 * 16 + to) * CK + ck]);
        const float4 w2v = *reinterpret_cast<const float4*>(&wgt[(2 * 16 + to) * CK + ck]);
        const float4 w3v = *reinterpret_cast<const float4*>(&wgt[(3 * 16 + to) * CK + ck]);
        acc0 = fmaf(sv.x, w0v.x, acc0); acc0 = fmaf(sv.y, w0v.y, acc0);
        acc0 = fmaf(sv.z, w0v.z, acc0); acc0 = fmaf(sv.w, w0v.w, acc0);
        acc1 = fmaf(sv.x, w1v.x, acc1); acc1 = fmaf(sv.y, w1v.y, acc1);
        acc1 = fmaf(sv.z, w1v.z, acc1); acc1 = fmaf(sv.w, w1v.w, acc1);
        acc2 = fmaf(sv.x, w2v.x, acc2); acc2 = fmaf(sv.y, w2v.y, acc2);
        acc2 = fmaf(sv.z, w2v.z, acc2); acc2 = fmaf(sv.w, w2v.w, acc2);
        acc3 = fmaf(sv.x, w3v.x, acc3); acc3 = fmaf(sv.y, w3v.y, acc3);
        acc3 = fmaf(sv.z, w3v.z, acc3); acc3 = fmaf(sv.w, w3v.w, acc3);
    }
    int wcol = w0 + tp;
    y[((b * Cout + (0 * 16 + to)) * H + h) * W + wcol] = acc0 + bias[0 * 16 + to];
    y[((b * Cout + (1 * 16 + to)) * H + h) * W + wcol] = acc1 + bias[1 * 16 + to];
    y[((b * Cout + (2 * 16 + to)) * H + h) * W + wcol] = acc2 + bias[2 * 16 + to];
    y[((b * Cout + (3 * 16 + to)) * H + h) * W + wcol] = acc3 + bias[3 * 16 + to];
}

extern "C" void kernel_launch(void* const* d_in, const int* in_sizes, int n_in,
                              void* d_out, int out_size, void* d_ws, size_t ws_size,
                              hipStream_t stream) {
    const float* x         = (const float*)d_in[0];
    const float* offset_in = (const float*)d_in[1];
    const float* weight    = (const float*)d_in[2];
    const float* bias      = (const float*)d_in[3];
    const float* cm_w      = (const float*)d_in[4];
    const float* cm_b      = (const float*)d_in[5];

    float* out  = (float*)d_out;
    float* offs = out;                    // output 0: (B,18,H,W)
    float* yout = out + OFFSET_ELEMS;     // output 1: (B,64,H,W)

    if (ws_size >= WS_NEEDED) {
        unsigned short* x_t   = (unsigned short*)((char*)d_ws + XT_OFF);
        unsigned short* o_t   = (unsigned short*)((char*)d_ws + OT_OFF);
        unsigned short* wfrag = (unsigned short*)((char*)d_ws + WB_OFF);
        unsigned short* cfrag = (unsigned short*)((char*)d_ws + CMB_OFF);

        prep_all<<<2048 + 64, 256, 0, stream>>>(x, offset_in, weight, cm_w,
                                                x_t, o_t, wfrag, cfrag);
        dcn_fused<<<B * H * (W / PIX), 256, 0, stream>>>(x_t, o_t, wfrag, cfrag,
                                                         cm_b, bias, offs, yout);
    } else {
        offset_conv_fb<<<OFFSET_ELEMS / 256, 256, 0, stream>>>(offset_in, cm_w, cm_b, offs);
        deform_gemm_fb<<<B * H * (W / 16), 256, 0, stream>>>(x, offs, weight, bias, yout);
    }
}